// Round 4
// baseline (137.767 us; speedup 1.0000x reference)
//
#include <hip/hip_runtime.h>
#include <stdint.h>
#include <string.h>
#include <algorithm>

#define NV 4096
#define NPOOL 1024
#define NB 8
#define KNB 16
#define REMOVED 0xFFFFFFFFu

struct SIdx { unsigned short v[NPOOL]; };  // 2 KB by-value kernel arg

// ---------------- Threefry-2x32 (JAX-compatible, 20 rounds), host ----------
static inline void tf2x32_host(uint32_t k0, uint32_t k1,
                               uint32_t c0, uint32_t c1,
                               uint32_t& o0, uint32_t& o1) {
  uint32_t ks0 = k0, ks1 = k1, ks2 = k0 ^ k1 ^ 0x1BD11BDAu;
  uint32_t x0 = c0 + ks0, x1 = c1 + ks1;
#define TFR(r) { x0 += x1; x1 = (x1 << (r)) | (x1 >> (32 - (r))); x1 ^= x0; }
  TFR(13) TFR(15) TFR(26) TFR(6)
  x0 += ks1; x1 += ks2 + 1u;
  TFR(17) TFR(29) TFR(16) TFR(24)
  x0 += ks2; x1 += ks0 + 2u;
  TFR(13) TFR(15) TFR(26) TFR(6)
  x0 += ks0; x1 += ks1 + 3u;
  TFR(17) TFR(29) TFR(16) TFR(24)
  x0 += ks1; x1 += ks2 + 4u;
  TFR(13) TFR(15) TFR(26) TFR(6)
  x0 += ks2; x1 += ks0 + 5u;
#undef TFR
  o0 = x0; o1 = x1;
}

// Host: replicate jax.random.permutation(key(42), 4096)[:1024]  (validated absmax=0)
static void compute_sample_idx(SIdx& out) {
  static_assert(sizeof(SIdx) == 2048, "kernarg size");
  uint64_t arr[NV];
  uint16_t x[NV], tmp[NV];
  for (int i = 0; i < NV; ++i) x[i] = (uint16_t)i;
  uint32_t kh = 0u, kl = 42u;
  for (int round = 0; round < 2; ++round) {
    uint32_t nkh, nkl, sh, sl, t0, t1;
    tf2x32_host(kh, kl, 0u, 0u, nkh, nkl);
    tf2x32_host(kh, kl, 0u, 1u, sh, sl);
    kh = nkh; kl = nkl;
    for (int i = 0; i < NV; ++i) {
      tf2x32_host(sh, sl, 0u, (uint32_t)i, t0, t1);
      arr[i] = ((uint64_t)(t0 ^ t1) << 32) | (uint32_t)i;
    }
    std::sort(arr, arr + NV);
    for (int i = 0; i < NV; ++i) tmp[i] = x[(uint32_t)(arr[i] & 0xffffffffu)];
    memcpy(x, tmp, sizeof(x));
  }
  for (int i = 0; i < NPOOL; ++i) out.v[i] = x[i];
}

// ---------------- K1: 256 threads / query. Register-resident distances,
// cached-lane-min top-16 extraction, fused gather/max.
__global__ __launch_bounds__(256) void knn_pool_kernel(
    const float* __restrict__ vertices, const float* __restrict__ fm,
    const SIdx sidx,
    float* __restrict__ outV, float* __restrict__ outF) {
  __shared__ unsigned long long wmin[4];
  __shared__ int wlist[KNB];

  const int tid = threadIdx.x;
  const int lane = tid & 63;
  const int warp = tid >> 6;
  const int q = blockIdx.x;        // 0..8191
  const int b = q >> 10;
  const int i = q & 1023;
  const int n = (int)sidx.v[i];

  const float* vb = vertices + (size_t)b * NV * 3;
  const float qx = vb[n * 3 + 0], qy = vb[n * 3 + 1], qz = vb[n * 3 + 2];
  // quadratic[n]: plain mul/add (XLA reduce of squares) — validated arithmetic
  const float qn = __fadd_rn(__fadd_rn(__fmul_rn(qx, qx), __fmul_rn(qy, qy)),
                             __fmul_rn(qz, qz));

  // distances, register-resident: thread owns m = t*256 + tid, t = 0..15
  uint32_t d[16];
#pragma unroll
  for (int t = 0; t < 16; ++t) {
    const int m = (t << 8) + tid;
    const float cx = vb[m * 3 + 0], cy = vb[m * 3 + 1], cz = vb[m * 3 + 2];
    const float inner = __fmaf_rn(cz, qz, __fmaf_rn(cy, qy, __fmul_rn(cx, qx)));
    const float qm = __fadd_rn(__fadd_rn(__fmul_rn(cx, cx), __fmul_rn(cy, cy)),
                               __fmul_rn(cz, cz));
    const float dist = __fadd_rn(__fadd_rn(__fmul_rn(-2.0f, inner), qm), qn);
    d[t] = (m == n) ? REMOVED : __float_as_uint(dist);  // positive floats: uint order
  }

  uint32_t mask = 0;   // removal mask, bit t
  uint32_t cv, cm;     // cached per-thread min (value bits, global index m)

#define RECOMPUTE_MIN()                                            \
  {                                                                \
    uint32_t bv = REMOVED; int bt = 0;                             \
    _Pragma("unroll")                                              \
    for (int t = 0; t < 16; ++t) {                                 \
      const uint32_t v = (mask & (1u << t)) ? REMOVED : d[t];      \
      if (v < bv) { bv = v; bt = t; }                              \
    }                                                              \
    cv = bv; cm = (uint32_t)((bt << 8) + tid);                     \
  }

  RECOMPUTE_MIN();

  for (int s = 0; s < KNB; ++s) {
    // intra-wave reduce of cached minima, (dist, index) lexicographic
    uint32_t rv = cv, rm = cm;
    for (int off = 32; off > 0; off >>= 1) {
      const uint32_t ov = (uint32_t)__shfl_down((int)rv, off);
      const uint32_t om = (uint32_t)__shfl_down((int)rm, off);
      if (ov < rv || (ov == rv && om < rm)) { rv = ov; rm = om; }
    }
    if (lane == 0) wmin[warp] = ((unsigned long long)rv << 32) | rm;
    __syncthreads();

    // cross-wave merge: integer order on (dist<<32)|m == lex order on (dist, m)
    unsigned long long p0 = wmin[0], p1 = wmin[1];
    unsigned long long p2 = wmin[2], p3 = wmin[3];
    unsigned long long pa = (p0 < p1) ? p0 : p1;
    unsigned long long pb = (p2 < p3) ? p2 : p3;
    const int w = (int)(((pa < pb) ? pa : pb) & 0xFFFFFFFFu);  // uniform winner

    if (tid == 0) wlist[s] = w;
    if (tid == (w & 255)) mask |= 1u << (w >> 8);    // remove winner
    if (warp == ((w >> 6) & 3)) RECOMPUTE_MIN();     // only owner wave rescans
    __syncthreads();
  }

  // fused gather + max: each thread owns one feature channel
  const float* fmb = fm + (size_t)b * NV * 256;
  float af = -INFINITY;
#pragma unroll
  for (int s = 0; s < KNB; ++s) {
    const int w = wlist[s];
    af = fmaxf(af, fmb[(size_t)w * 256 + tid]);
  }
  outF[((size_t)b * NPOOL + i) * 256 + tid] = af;

  if (tid < 3) {
    outV[((size_t)b * NPOOL + i) * 3 + tid] = vb[n * 3 + tid];
  }
#undef RECOMPUTE_MIN
}

extern "C" void kernel_launch(void* const* d_in, const int* in_sizes, int n_in,
                              void* d_out, int out_size, void* d_ws, size_t ws_size,
                              hipStream_t stream) {
  const float* vertices = (const float*)d_in[0];
  const float* fm = (const float*)d_in[1];
  float* out = (float*)d_out;
  float* outV = out;                      // (8, 1024, 3)
  float* outF = out + NB * NPOOL * 3;     // (8, 1024, 256)

  SIdx sidx;
  compute_sample_idx(sidx);               // pure host constant of key(42)

  knn_pool_kernel<<<NB * NPOOL, 256, 0, stream>>>(vertices, fm, sidx, outV, outF);
}

// Round 6
// 69.973 us; speedup vs baseline: 1.9688x; 1.9688x over previous
//
#include <hip/hip_runtime.h>
#include <stdint.h>
#include <string.h>
#include <algorithm>

#define NV 4096
#define NPOOL 1024
#define NB 8
#define KNB 16
#define REMOVED 0xFFFFFFFFu

struct SIdx { unsigned short v[NPOOL]; };  // 2 KB by-value kernel arg

// ---------------- Threefry-2x32 (JAX-compatible, 20 rounds), host ----------
static inline void tf2x32_host(uint32_t k0, uint32_t k1,
                               uint32_t c0, uint32_t c1,
                               uint32_t& o0, uint32_t& o1) {
  uint32_t ks0 = k0, ks1 = k1, ks2 = k0 ^ k1 ^ 0x1BD11BDAu;
  uint32_t x0 = c0 + ks0, x1 = c1 + ks1;
#define TFR(r) { x0 += x1; x1 = (x1 << (r)) | (x1 >> (32 - (r))); x1 ^= x0; }
  TFR(13) TFR(15) TFR(26) TFR(6)
  x0 += ks1; x1 += ks2 + 1u;
  TFR(17) TFR(29) TFR(16) TFR(24)
  x0 += ks2; x1 += ks0 + 2u;
  TFR(13) TFR(15) TFR(26) TFR(6)
  x0 += ks0; x1 += ks1 + 3u;
  TFR(17) TFR(29) TFR(16) TFR(24)
  x0 += ks1; x1 += ks2 + 4u;
  TFR(13) TFR(15) TFR(26) TFR(6)
  x0 += ks2; x1 += ks0 + 5u;
#undef TFR
  o0 = x0; o1 = x1;
}

// Host: replicate jax.random.permutation(key(42), 4096)[:1024]  (validated absmax=0)
static void compute_sample_idx(SIdx& out) {
  static_assert(sizeof(SIdx) == 2048, "kernarg size");
  uint64_t arr[NV];
  uint16_t x[NV], tmp[NV];
  for (int i = 0; i < NV; ++i) x[i] = (uint16_t)i;
  uint32_t kh = 0u, kl = 42u;
  for (int round = 0; round < 2; ++round) {
    uint32_t nkh, nkl, sh, sl, t0, t1;
    tf2x32_host(kh, kl, 0u, 0u, nkh, nkl);
    tf2x32_host(kh, kl, 0u, 1u, sh, sl);
    kh = nkh; kl = nkl;
    for (int i = 0; i < NV; ++i) {
      tf2x32_host(sh, sl, 0u, (uint32_t)i, t0, t1);
      arr[i] = ((uint64_t)(t0 ^ t1) << 32) | (uint32_t)i;
    }
    std::sort(arr, arr + NV);
    for (int i = 0; i < NV; ++i) tmp[i] = x[(uint32_t)(arr[i] & 0xffffffffu)];
    memcpy(x, tmp, sizeof(x));
  }
  for (int i = 0; i < NPOOL; ++i) out.v[i] = x[i];
}

__device__ __forceinline__ unsigned long long shflx64(unsigned long long v, int m) {
  const int lo = __shfl_xor((int)(uint32_t)v, m);
  const int hi = __shfl_xor((int)(uint32_t)(v >> 32), m);
  return ((unsigned long long)(uint32_t)hi << 32) | (uint32_t)lo;
}

// ---------------- K1: 256 threads / query. Register distances + histogram
// top-16 set selection + fused gather/max.
__global__ __launch_bounds__(256) void knn_pool_kernel(
    const float* __restrict__ vertices, const float* __restrict__ fm,
    const SIdx sidx,
    float* __restrict__ outV, float* __restrict__ outF) {
  __shared__ uint32_t hist[1024];
  __shared__ unsigned long long cand[64];
  __shared__ unsigned long long wmin[4];
  __shared__ int winners[KNB];
  __shared__ int s_nwin, s_ncand, s_binB, s_cbelow;

  const int tid = threadIdx.x;
  const int lane = tid & 63;
  const int warp = tid >> 6;
  const int q = blockIdx.x;        // 0..8191
  const int b = q >> 10;
  const int i = q & 1023;
  const int n = (int)sidx.v[i];

  const float* vb = vertices + (size_t)b * NV * 3;
  const float qx = vb[n * 3 + 0], qy = vb[n * 3 + 1], qz = vb[n * 3 + 2];
  // quadratic[n]: plain mul/add (XLA reduce of squares) — validated arithmetic
  const float qn = __fadd_rn(__fadd_rn(__fmul_rn(qx, qx), __fmul_rn(qy, qy)),
                             __fmul_rn(qz, qz));

  // distances, register-resident: thread owns m = t*256 + tid, t = 0..15
  uint32_t d[16];
#pragma unroll
  for (int t = 0; t < 16; ++t) {
    const int m = (t << 8) + tid;
    const float cx = vb[m * 3 + 0], cy = vb[m * 3 + 1], cz = vb[m * 3 + 2];
    const float inner = __fmaf_rn(cz, qz, __fmaf_rn(cy, qy, __fmul_rn(cx, qx)));
    const float qm = __fadd_rn(__fadd_rn(__fmul_rn(cx, cx), __fmul_rn(cy, cy)),
                               __fmul_rn(cz, cz));
    const float dist = __fadd_rn(__fadd_rn(__fmul_rn(-2.0f, inner), qm), qn);
    d[t] = (m == n) ? REMOVED : __float_as_uint(dist);  // validated uint order
  }

  // histogram of top-10 bits (monotone map of the validated uint order)
  hist[tid] = 0; hist[tid + 256] = 0; hist[tid + 512] = 0; hist[tid + 768] = 0;
  if (tid == 0) { s_nwin = 0; s_ncand = 0; }
  __syncthreads();
#pragma unroll
  for (int t = 0; t < 16; ++t) atomicAdd(&hist[d[t] >> 22], 1u);
  __syncthreads();

  // one wave: find crossing bin B (cum crosses KNB) and c_below
  if (warp == 0) {
    uint32_t s = 0;
#pragma unroll
    for (int j = 0; j < 16; ++j) s += hist[lane * 16 + j];
    uint32_t inc = s;
    for (int off = 1; off < 64; off <<= 1) {
      const uint32_t o = (uint32_t)__shfl_up((int)inc, off);
      if (lane >= off) inc += o;
    }
    const uint32_t pre = inc - s;
    const bool cross = (pre < KNB) && (inc >= KNB);
    const unsigned long long bal = __ballot(cross);
    const int leader = __ffsll((unsigned long long)bal) - 1;
    if (lane == leader) {
      uint32_t c = pre;
      int B = lane * 16 + 15;
      for (int j = 0; j < 16; ++j) {
        const uint32_t h = hist[lane * 16 + j];
        if (c + h >= KNB) { B = lane * 16 + j; break; }
        c += h;
      }
      s_binB = B; s_cbelow = (int)c;
    }
  }
  __syncthreads();

  const int B = s_binB;
  const int cbelow = s_cbelow;
  const uint32_t cntB = hist[B];
  const int need = KNB - cbelow;   // >= 1, <= cntB

  if (cntB <= 64) {
    // definite winners (bins < B) + boundary-bin candidates
#pragma unroll
    for (int t = 0; t < 16; ++t) {
      const uint32_t v = d[t];
      const int bin = (int)(v >> 22);
      if (bin < B) {
        const int s = atomicAdd(&s_nwin, 1);
        winners[s] = (t << 8) + tid;
      } else if (bin == B) {
        const int s = atomicAdd(&s_ncand, 1);
        cand[s] = ((unsigned long long)v << 32) | (uint32_t)((t << 8) + tid);
      }
    }
    __syncthreads();
    if (warp == 0) {
      const int C = s_ncand;
      unsigned long long v = (lane < C) ? cand[lane] : 0xFFFFFFFFFFFFFFFFull;
      // full bitonic sort of 64 u64 (integer order == lex (dist,index) order)
      for (int k = 2; k <= 64; k <<= 1)
        for (int j = k >> 1; j > 0; j >>= 1) {
          const unsigned long long o = shflx64(v, j);
          const bool up = ((lane & k) == 0);
          const bool takeMin = (((lane & j) == 0) == up);
          const bool repl = takeMin ? (o < v) : (o > v);
          v = repl ? o : v;
        }
      if (lane < need) winners[cbelow + lane] = (int)(v & 0xFFFFFFFFu);
    }
    __syncthreads();
  } else {
    // rare fallback: validated iterative extraction, restricted to bin B
#pragma unroll 1
    for (int t = 0; t < 16; ++t) {  // definite winners still collected
      const uint32_t v = d[t];
      if ((int)(v >> 22) < B) {
        const int s = atomicAdd(&s_nwin, 1);
        winners[s] = (t << 8) + tid;
      }
    }
    __syncthreads();
    uint32_t mask = 0;
    for (int r = 0; r < need; ++r) {
      uint32_t bv = REMOVED, bm = 0xFFFFFFFFu;
#pragma unroll
      for (int t = 0; t < 16; ++t) {
        const uint32_t v = (((mask >> t) & 1u) || ((int)(d[t] >> 22) != B))
                               ? REMOVED : d[t];
        const uint32_t m = (uint32_t)((t << 8) + tid);
        if (v < bv || (v == bv && m < bm)) { bv = v; bm = m; }
      }
      for (int off = 32; off > 0; off >>= 1) {
        const uint32_t ov = (uint32_t)__shfl_down((int)bv, off);
        const uint32_t om = (uint32_t)__shfl_down((int)bm, off);
        if (ov < bv || (ov == bv && om < bm)) { bv = ov; bm = om; }
      }
      if (lane == 0) wmin[warp] = ((unsigned long long)bv << 32) | bm;
      __syncthreads();
      const unsigned long long p0 = wmin[0], p1 = wmin[1];
      const unsigned long long p2 = wmin[2], p3 = wmin[3];
      const unsigned long long pa = (p0 < p1) ? p0 : p1;
      const unsigned long long pb = (p2 < p3) ? p2 : p3;
      const int w = (int)(((pa < pb) ? pa : pb) & 0xFFFFFFFFu);
      if (tid == 0) winners[cbelow + r] = w;
      if (tid == (w & 255)) mask |= 1u << (w >> 8);
      __syncthreads();
    }
  }

  // fused gather + max over the winner set (order-invariant)
  const float* fmb = fm + (size_t)b * NV * 256;
  float af = -INFINITY;
#pragma unroll
  for (int s = 0; s < KNB; ++s) {
    const int w = winners[s];
    af = fmaxf(af, fmb[(size_t)w * 256 + tid]);
  }
  outF[((size_t)b * NPOOL + i) * 256 + tid] = af;

  if (tid < 3) {
    outV[((size_t)b * NPOOL + i) * 3 + tid] = vb[n * 3 + tid];
  }
}

extern "C" void kernel_launch(void* const* d_in, const int* in_sizes, int n_in,
                              void* d_out, int out_size, void* d_ws, size_t ws_size,
                              hipStream_t stream) {
  const float* vertices = (const float*)d_in[0];
  const float* fm = (const float*)d_in[1];
  float* out = (float*)d_out;
  float* outV = out;                      // (8, 1024, 3)
  float* outF = out + NB * NPOOL * 3;     // (8, 1024, 256)

  SIdx sidx;
  compute_sample_idx(sidx);               // pure host constant of key(42)

  knn_pool_kernel<<<NB * NPOOL, 256, 0, stream>>>(vertices, fm, sidx, outV, outF);
}

// Round 7
// 63.934 us; speedup vs baseline: 2.1548x; 1.0945x over previous
//
#include <hip/hip_runtime.h>
#include <stdint.h>
#include <string.h>
#include <algorithm>

#define NV 4096
#define NPOOL 1024
#define NB 8
#define KNB 16
#define REMOVED 0xFFFFFFFFu

struct SIdx { unsigned short v[NPOOL]; };  // 2 KB by-value kernel arg

// ---------------- Threefry-2x32 (JAX-compatible, 20 rounds), host ----------
static inline void tf2x32_host(uint32_t k0, uint32_t k1,
                               uint32_t c0, uint32_t c1,
                               uint32_t& o0, uint32_t& o1) {
  uint32_t ks0 = k0, ks1 = k1, ks2 = k0 ^ k1 ^ 0x1BD11BDAu;
  uint32_t x0 = c0 + ks0, x1 = c1 + ks1;
#define TFR(r) { x0 += x1; x1 = (x1 << (r)) | (x1 >> (32 - (r))); x1 ^= x0; }
  TFR(13) TFR(15) TFR(26) TFR(6)
  x0 += ks1; x1 += ks2 + 1u;
  TFR(17) TFR(29) TFR(16) TFR(24)
  x0 += ks2; x1 += ks0 + 2u;
  TFR(13) TFR(15) TFR(26) TFR(6)
  x0 += ks0; x1 += ks1 + 3u;
  TFR(17) TFR(29) TFR(16) TFR(24)
  x0 += ks1; x1 += ks2 + 4u;
  TFR(13) TFR(15) TFR(26) TFR(6)
  x0 += ks2; x1 += ks0 + 5u;
#undef TFR
  o0 = x0; o1 = x1;
}

// Host: replicate jax.random.permutation(key(42), 4096)[:1024]  (validated absmax=0)
static void compute_sample_idx(SIdx& out) {
  static_assert(sizeof(SIdx) == 2048, "kernarg size");
  uint64_t arr[NV];
  uint16_t x[NV], tmp[NV];
  for (int i = 0; i < NV; ++i) x[i] = (uint16_t)i;
  uint32_t kh = 0u, kl = 42u;
  for (int round = 0; round < 2; ++round) {
    uint32_t nkh, nkl, sh, sl, t0, t1;
    tf2x32_host(kh, kl, 0u, 0u, nkh, nkl);
    tf2x32_host(kh, kl, 0u, 1u, sh, sl);
    kh = nkh; kl = nkl;
    for (int i = 0; i < NV; ++i) {
      tf2x32_host(sh, sl, 0u, (uint32_t)i, t0, t1);
      arr[i] = ((uint64_t)(t0 ^ t1) << 32) | (uint32_t)i;
    }
    std::sort(arr, arr + NV);
    for (int i = 0; i < NV; ++i) tmp[i] = x[(uint32_t)(arr[i] & 0xffffffffu)];
    memcpy(x, tmp, sizeof(x));
  }
  for (int i = 0; i < NPOOL; ++i) out.v[i] = x[i];
}

__device__ __forceinline__ unsigned long long shflx64(unsigned long long v, int m) {
  const int lo = __shfl_xor((int)(uint32_t)v, m);
  const int hi = __shfl_xor((int)(uint32_t)(v >> 32), m);
  return ((unsigned long long)(uint32_t)hi << 32) | (uint32_t)lo;
}

// ---------------- K1: 256 threads / query. float4 vertex loads, register
// distances, histogram top-16 set selection, fused gather/max.
// Thread owns candidates m = tid*16 + t (192 contiguous bytes -> 12 dwordx4).
__global__ __launch_bounds__(256) void knn_pool_kernel(
    const float* __restrict__ vertices, const float* __restrict__ fm,
    const SIdx sidx,
    float* __restrict__ outV, float* __restrict__ outF) {
  __shared__ uint32_t hist[1024];
  __shared__ unsigned long long cand[64];
  __shared__ unsigned long long wmin[4];
  __shared__ int winners[KNB];
  __shared__ int s_nwin, s_ncand, s_binB, s_cbelow;

  const int tid = threadIdx.x;
  const int lane = tid & 63;
  const int warp = tid >> 6;
  const int q = blockIdx.x;        // 0..8191
  const int b = q & 7;             // XCD-aware: batch b -> XCD b (8192%8==0, bijective)
  const int i = q >> 3;
  const int n = (int)sidx.v[i];

  const float* vb = vertices + (size_t)b * NV * 3;
  const float qx = vb[n * 3 + 0], qy = vb[n * 3 + 1], qz = vb[n * 3 + 2];
  // quadratic[n]: plain mul/add (XLA reduce of squares) — validated arithmetic
  const float qn = __fadd_rn(__fadd_rn(__fmul_rn(qx, qx), __fmul_rn(qy, qy)),
                             __fmul_rn(qz, qz));

  // 12 independent float4 loads: this thread's 16 vertices, 192 B contiguous
  const float4* vb4 = (const float4*)vb + tid * 12;
  float f[48];
#pragma unroll
  for (int j = 0; j < 12; ++j) {
    const float4 v4 = vb4[j];
    f[4 * j + 0] = v4.x; f[4 * j + 1] = v4.y;
    f[4 * j + 2] = v4.z; f[4 * j + 3] = v4.w;
  }

  uint32_t d[16];
#pragma unroll
  for (int t = 0; t < 16; ++t) {
    const int m = (tid << 4) + t;
    const float cx = f[3 * t + 0], cy = f[3 * t + 1], cz = f[3 * t + 2];
    const float inner = __fmaf_rn(cz, qz, __fmaf_rn(cy, qy, __fmul_rn(cx, qx)));
    const float qm = __fadd_rn(__fadd_rn(__fmul_rn(cx, cx), __fmul_rn(cy, cy)),
                               __fmul_rn(cz, cz));
    const float dist = __fadd_rn(__fadd_rn(__fmul_rn(-2.0f, inner), qm), qn);
    d[t] = (m == n) ? REMOVED : __float_as_uint(dist);  // validated uint order
  }

  // histogram of top-10 bits (monotone map of the validated uint order)
  hist[tid] = 0; hist[tid + 256] = 0; hist[tid + 512] = 0; hist[tid + 768] = 0;
  if (tid == 0) { s_nwin = 0; s_ncand = 0; }
  __syncthreads();
#pragma unroll
  for (int t = 0; t < 16; ++t) atomicAdd(&hist[d[t] >> 22], 1u);
  __syncthreads();

  // one wave: find crossing bin B (cum crosses KNB) and c_below
  if (warp == 0) {
    uint32_t s = 0;
#pragma unroll
    for (int j = 0; j < 16; ++j) s += hist[lane * 16 + j];
    uint32_t inc = s;
    for (int off = 1; off < 64; off <<= 1) {
      const uint32_t o = (uint32_t)__shfl_up((int)inc, off);
      if (lane >= off) inc += o;
    }
    const uint32_t pre = inc - s;
    const bool cross = (pre < KNB) && (inc >= KNB);
    const unsigned long long bal = __ballot(cross);
    const int leader = __ffsll((unsigned long long)bal) - 1;
    if (lane == leader) {
      uint32_t c = pre;
      int B = lane * 16 + 15;
      for (int j = 0; j < 16; ++j) {
        const uint32_t h = hist[lane * 16 + j];
        if (c + h >= KNB) { B = lane * 16 + j; break; }
        c += h;
      }
      s_binB = B; s_cbelow = (int)c;
    }
  }
  __syncthreads();

  const int B = s_binB;
  const int cbelow = s_cbelow;
  const uint32_t cntB = hist[B];
  const int need = KNB - cbelow;   // >= 1, <= cntB

  if (cntB <= 64) {
    // definite winners (bins < B) + boundary-bin candidates
#pragma unroll
    for (int t = 0; t < 16; ++t) {
      const uint32_t v = d[t];
      const int bin = (int)(v >> 22);
      if (bin < B) {
        const int s = atomicAdd(&s_nwin, 1);
        winners[s] = (tid << 4) + t;
      } else if (bin == B) {
        const int s = atomicAdd(&s_ncand, 1);
        cand[s] = ((unsigned long long)v << 32) | (uint32_t)((tid << 4) + t);
      }
    }
    __syncthreads();
    if (warp == 0) {
      const int C = s_ncand;
      unsigned long long v = (lane < C) ? cand[lane] : 0xFFFFFFFFFFFFFFFFull;
      // full bitonic sort of 64 u64 (integer order == lex (dist,index) order)
      for (int k = 2; k <= 64; k <<= 1)
        for (int j = k >> 1; j > 0; j >>= 1) {
          const unsigned long long o = shflx64(v, j);
          const bool up = ((lane & k) == 0);
          const bool takeMin = (((lane & j) == 0) == up);
          const bool repl = takeMin ? (o < v) : (o > v);
          v = repl ? o : v;
        }
      if (lane < need) winners[cbelow + lane] = (int)(v & 0xFFFFFFFFu);
    }
    __syncthreads();
  } else {
    // rare fallback: validated iterative extraction, restricted to bin B
#pragma unroll 1
    for (int t = 0; t < 16; ++t) {  // definite winners still collected
      const uint32_t v = d[t];
      if ((int)(v >> 22) < B) {
        const int s = atomicAdd(&s_nwin, 1);
        winners[s] = (tid << 4) + t;
      }
    }
    __syncthreads();
    uint32_t mask = 0;
    for (int r = 0; r < need; ++r) {
      uint32_t bv = REMOVED, bm = 0xFFFFFFFFu;
#pragma unroll
      for (int t = 0; t < 16; ++t) {
        const uint32_t v = (((mask >> t) & 1u) || ((int)(d[t] >> 22) != B))
                               ? REMOVED : d[t];
        const uint32_t m = (uint32_t)((tid << 4) + t);
        if (v < bv || (v == bv && m < bm)) { bv = v; bm = m; }
      }
      for (int off = 32; off > 0; off >>= 1) {
        const uint32_t ov = (uint32_t)__shfl_down((int)bv, off);
        const uint32_t om = (uint32_t)__shfl_down((int)bm, off);
        if (ov < bv || (ov == bv && om < bm)) { bv = ov; bm = om; }
      }
      if (lane == 0) wmin[warp] = ((unsigned long long)bv << 32) | bm;
      __syncthreads();
      const unsigned long long p0 = wmin[0], p1 = wmin[1];
      const unsigned long long p2 = wmin[2], p3 = wmin[3];
      const unsigned long long pa = (p0 < p1) ? p0 : p1;
      const unsigned long long pb = (p2 < p3) ? p2 : p3;
      const int w = (int)(((pa < pb) ? pa : pb) & 0xFFFFFFFFu);
      if (tid == 0) winners[cbelow + r] = w;
      if (tid == (w >> 4)) mask |= 1u << (w & 15);
      __syncthreads();
    }
  }

  // fused gather + max over the winner set (order-invariant)
  const float* fmb = fm + (size_t)b * NV * 256;
  float af = -INFINITY;
#pragma unroll
  for (int s = 0; s < KNB; ++s) {
    const int w = winners[s];
    af = fmaxf(af, fmb[(size_t)w * 256 + tid]);
  }
  outF[((size_t)b * NPOOL + i) * 256 + tid] = af;

  if (tid < 3) {
    outV[((size_t)b * NPOOL + i) * 3 + tid] = vb[n * 3 + tid];
  }
}

extern "C" void kernel_launch(void* const* d_in, const int* in_sizes, int n_in,
                              void* d_out, int out_size, void* d_ws, size_t ws_size,
                              hipStream_t stream) {
  const float* vertices = (const float*)d_in[0];
  const float* fm = (const float*)d_in[1];
  float* out = (float*)d_out;
  float* outV = out;                      // (8, 1024, 3)
  float* outF = out + NB * NPOOL * 3;     // (8, 1024, 256)

  SIdx sidx;
  compute_sample_idx(sidx);               // pure host constant of key(42)

  knn_pool_kernel<<<NB * NPOOL, 256, 0, stream>>>(vertices, fm, sidx, outV, outF);
}

// Round 8
// 55.269 us; speedup vs baseline: 2.4926x; 1.1568x over previous
//
#include <hip/hip_runtime.h>
#include <stdint.h>
#include <string.h>
#include <algorithm>

#define NV 4096
#define NPOOL 1024
#define NB 8
#define KNB 16
#define REMOVED 0xFFFFFFFFu

struct SIdx { unsigned short v[NPOOL]; };  // 2 KB by-value kernel arg

// ---------------- Threefry-2x32 (JAX-compatible, 20 rounds), host ----------
static inline void tf2x32_host(uint32_t k0, uint32_t k1,
                               uint32_t c0, uint32_t c1,
                               uint32_t& o0, uint32_t& o1) {
  uint32_t ks0 = k0, ks1 = k1, ks2 = k0 ^ k1 ^ 0x1BD11BDAu;
  uint32_t x0 = c0 + ks0, x1 = c1 + ks1;
#define TFR(r) { x0 += x1; x1 = (x1 << (r)) | (x1 >> (32 - (r))); x1 ^= x0; }
  TFR(13) TFR(15) TFR(26) TFR(6)
  x0 += ks1; x1 += ks2 + 1u;
  TFR(17) TFR(29) TFR(16) TFR(24)
  x0 += ks2; x1 += ks0 + 2u;
  TFR(13) TFR(15) TFR(26) TFR(6)
  x0 += ks0; x1 += ks1 + 3u;
  TFR(17) TFR(29) TFR(16) TFR(24)
  x0 += ks1; x1 += ks2 + 4u;
  TFR(13) TFR(15) TFR(26) TFR(6)
  x0 += ks2; x1 += ks0 + 5u;
#undef TFR
  o0 = x0; o1 = x1;
}

// Host: replicate jax.random.permutation(key(42), 4096)[:1024]  (validated absmax=0)
static void compute_sample_idx(SIdx& out) {
  static_assert(sizeof(SIdx) == 2048, "kernarg size");
  uint64_t arr[NV];
  uint16_t x[NV], tmp[NV];
  for (int i = 0; i < NV; ++i) x[i] = (uint16_t)i;
  uint32_t kh = 0u, kl = 42u;
  for (int round = 0; round < 2; ++round) {
    uint32_t nkh, nkl, sh, sl, t0, t1;
    tf2x32_host(kh, kl, 0u, 0u, nkh, nkl);
    tf2x32_host(kh, kl, 0u, 1u, sh, sl);
    kh = nkh; kl = nkl;
    for (int i = 0; i < NV; ++i) {
      tf2x32_host(sh, sl, 0u, (uint32_t)i, t0, t1);
      arr[i] = ((uint64_t)(t0 ^ t1) << 32) | (uint32_t)i;
    }
    std::sort(arr, arr + NV);
    for (int i = 0; i < NV; ++i) tmp[i] = x[(uint32_t)(arr[i] & 0xffffffffu)];
    memcpy(x, tmp, sizeof(x));
  }
  for (int i = 0; i < NPOOL; ++i) out.v[i] = x[i];
}

// ---------------- K1: 256 threads / query. float4 vertex loads, register
// distances, histogram top-16 set selection (per-lane rank for boundary bin),
// fused gather/max. Thread owns candidates m = tid*16 + t.
__global__ __launch_bounds__(256) void knn_pool_kernel(
    const float* __restrict__ vertices, const float* __restrict__ fm,
    const SIdx sidx,
    float* __restrict__ outV, float* __restrict__ outF) {
  __shared__ uint32_t hist[1024];
  __shared__ unsigned long long cand[64];
  __shared__ unsigned long long wmin[4];
  __shared__ int winners[KNB];
  __shared__ int s_nwin, s_ncand, s_binB, s_cbelow;

  const int tid = threadIdx.x;
  const int lane = tid & 63;
  const int warp = tid >> 6;
  const int q = blockIdx.x;        // 0..8191
  const int b = q & 7;             // XCD-aware: batch b -> XCD b (bijective)
  const int i = q >> 3;
  const int n = (int)sidx.v[i];

  const float* vb = vertices + (size_t)b * NV * 3;
  const float qx = vb[n * 3 + 0], qy = vb[n * 3 + 1], qz = vb[n * 3 + 2];
  // quadratic[n]: plain mul/add (XLA reduce of squares) — validated arithmetic
  const float qn = __fadd_rn(__fadd_rn(__fmul_rn(qx, qx), __fmul_rn(qy, qy)),
                             __fmul_rn(qz, qz));

  // 12 independent float4 loads: this thread's 16 vertices, 192 B contiguous
  const float4* vb4 = (const float4*)vb + tid * 12;
  float f[48];
#pragma unroll
  for (int j = 0; j < 12; ++j) {
    const float4 v4 = vb4[j];
    f[4 * j + 0] = v4.x; f[4 * j + 1] = v4.y;
    f[4 * j + 2] = v4.z; f[4 * j + 3] = v4.w;
  }

  uint32_t d[16];
#pragma unroll
  for (int t = 0; t < 16; ++t) {
    const int m = (tid << 4) + t;
    const float cx = f[3 * t + 0], cy = f[3 * t + 1], cz = f[3 * t + 2];
    const float inner = __fmaf_rn(cz, qz, __fmaf_rn(cy, qy, __fmul_rn(cx, qx)));
    const float qm = __fadd_rn(__fadd_rn(__fmul_rn(cx, cx), __fmul_rn(cy, cy)),
                               __fmul_rn(cz, cz));
    const float dist = __fadd_rn(__fadd_rn(__fmul_rn(-2.0f, inner), qm), qn);
    d[t] = (m == n) ? REMOVED : __float_as_uint(dist);  // validated uint order
  }

  // histogram of top-10 bits (monotone map of the validated uint order)
  hist[tid] = 0; hist[tid + 256] = 0; hist[tid + 512] = 0; hist[tid + 768] = 0;
  if (tid == 0) { s_nwin = 0; s_ncand = 0; }
  __syncthreads();
#pragma unroll
  for (int t = 0; t < 16; ++t) atomicAdd(&hist[d[t] >> 22], 1u);
  __syncthreads();

  // one wave: find crossing bin B (cum crosses KNB) and c_below
  if (warp == 0) {
    uint32_t s = 0;
#pragma unroll
    for (int j = 0; j < 16; ++j) s += hist[lane * 16 + j];
    uint32_t inc = s;
    for (int off = 1; off < 64; off <<= 1) {
      const uint32_t o = (uint32_t)__shfl_up((int)inc, off);
      if (lane >= off) inc += o;
    }
    const uint32_t pre = inc - s;
    const bool cross = (pre < KNB) && (inc >= KNB);
    const unsigned long long bal = __ballot(cross);
    const int leader = __ffsll((unsigned long long)bal) - 1;
    if (lane == leader) {
      uint32_t c = pre;
      int B = lane * 16 + 15;
      for (int j = 0; j < 16; ++j) {
        const uint32_t h = hist[lane * 16 + j];
        if (c + h >= KNB) { B = lane * 16 + j; break; }
        c += h;
      }
      s_binB = B; s_cbelow = (int)c;
    }
  }
  __syncthreads();

  const int B = s_binB;
  const int cbelow = s_cbelow;
  const uint32_t cntB = hist[B];
  const int need = KNB - cbelow;   // >= 1, <= cntB

  if (cntB <= 64) {
    // definite winners (bins < B) + boundary-bin candidates
#pragma unroll
    for (int t = 0; t < 16; ++t) {
      const uint32_t v = d[t];
      const int bin = (int)(v >> 22);
      if (bin < B) {
        const int s = atomicAdd(&s_nwin, 1);
        winners[s] = (tid << 4) + t;
      } else if (bin == B) {
        const int s = atomicAdd(&s_ncand, 1);
        cand[s] = ((unsigned long long)v << 32) | (uint32_t)((tid << 4) + t);
      }
    }
    __syncthreads();
    if (warp == 0) {
      // per-lane rank selection: ranks unique (strict total order on
      // (dist,idx) packed u64); winners get deterministic positions.
      const int C = s_ncand;
      const unsigned long long me =
          (lane < C) ? cand[lane] : 0xFFFFFFFFFFFFFFFFull;
      int rank = 0;
      for (int j = 0; j < C; ++j) {        // cand[j]: LDS broadcast read
        rank += (cand[j] < me) ? 1 : 0;
      }
      if (lane < C && rank < need) winners[cbelow + rank] = (int)(me & 0xFFFFFFFFu);
    }
    __syncthreads();
  } else {
    // rare fallback: validated iterative extraction, restricted to bin B
#pragma unroll 1
    for (int t = 0; t < 16; ++t) {  // definite winners still collected
      const uint32_t v = d[t];
      if ((int)(v >> 22) < B) {
        const int s = atomicAdd(&s_nwin, 1);
        winners[s] = (tid << 4) + t;
      }
    }
    __syncthreads();
    uint32_t mask = 0;
    for (int r = 0; r < need; ++r) {
      uint32_t bv = REMOVED, bm = 0xFFFFFFFFu;
#pragma unroll
      for (int t = 0; t < 16; ++t) {
        const uint32_t v = (((mask >> t) & 1u) || ((int)(d[t] >> 22) != B))
                               ? REMOVED : d[t];
        const uint32_t m = (uint32_t)((tid << 4) + t);
        if (v < bv || (v == bv && m < bm)) { bv = v; bm = m; }
      }
      for (int off = 32; off > 0; off >>= 1) {
        const uint32_t ov = (uint32_t)__shfl_down((int)bv, off);
        const uint32_t om = (uint32_t)__shfl_down((int)bm, off);
        if (ov < bv || (ov == bv && om < bm)) { bv = ov; bm = om; }
      }
      if (lane == 0) wmin[warp] = ((unsigned long long)bv << 32) | bm;
      __syncthreads();
      const unsigned long long p0 = wmin[0], p1 = wmin[1];
      const unsigned long long p2 = wmin[2], p3 = wmin[3];
      const unsigned long long pa = (p0 < p1) ? p0 : p1;
      const unsigned long long pb = (p2 < p3) ? p2 : p3;
      const int w = (int)(((pa < pb) ? pa : pb) & 0xFFFFFFFFu);
      if (tid == 0) winners[cbelow + r] = w;
      if (tid == (w >> 4)) mask |= 1u << (w & 15);
      __syncthreads();
    }
  }

  // fused gather + max over the winner set (order-invariant)
  const float* fmb = fm + (size_t)b * NV * 256;
  float af = -INFINITY;
#pragma unroll
  for (int s = 0; s < KNB; ++s) {
    const int w = winners[s];
    af = fmaxf(af, fmb[(size_t)w * 256 + tid]);
  }
  outF[((size_t)b * NPOOL + i) * 256 + tid] = af;

  if (tid < 3) {
    outV[((size_t)b * NPOOL + i) * 3 + tid] = vb[n * 3 + tid];
  }
}

extern "C" void kernel_launch(void* const* d_in, const int* in_sizes, int n_in,
                              void* d_out, int out_size, void* d_ws, size_t ws_size,
                              hipStream_t stream) {
  const float* vertices = (const float*)d_in[0];
  const float* fm = (const float*)d_in[1];
  float* out = (float*)d_out;
  float* outV = out;                      // (8, 1024, 3)
  float* outF = out + NB * NPOOL * 3;     // (8, 1024, 256)

  SIdx sidx;
  compute_sample_idx(sidx);               // pure host constant of key(42)

  knn_pool_kernel<<<NB * NPOOL, 256, 0, stream>>>(vertices, fm, sidx, outV, outF);
}

// Round 9
// 40.962 us; speedup vs baseline: 3.3633x; 1.3493x over previous
//
#include <hip/hip_runtime.h>
#include <stdint.h>
#include <string.h>
#include <algorithm>

#define NV 4096
#define NPOOL 1024
#define NB 8
#define KNB 16
#define REMOVED 0xFFFFFFFFu
// bank-deconflicted histogram index: bin b -> word (b>>4) | ((b&15)<<6)
#define HIDX(b) ((((b) >> 4) | (((b) & 15) << 6)))

struct SIdx { unsigned short v[NPOOL]; };  // 2 KB by-value kernel arg

// ---------------- Threefry-2x32 (JAX-compatible, 20 rounds), host ----------
static inline void tf2x32_host(uint32_t k0, uint32_t k1,
                               uint32_t c0, uint32_t c1,
                               uint32_t& o0, uint32_t& o1) {
  uint32_t ks0 = k0, ks1 = k1, ks2 = k0 ^ k1 ^ 0x1BD11BDAu;
  uint32_t x0 = c0 + ks0, x1 = c1 + ks1;
#define TFR(r) { x0 += x1; x1 = (x1 << (r)) | (x1 >> (32 - (r))); x1 ^= x0; }
  TFR(13) TFR(15) TFR(26) TFR(6)
  x0 += ks1; x1 += ks2 + 1u;
  TFR(17) TFR(29) TFR(16) TFR(24)
  x0 += ks2; x1 += ks0 + 2u;
  TFR(13) TFR(15) TFR(26) TFR(6)
  x0 += ks0; x1 += ks1 + 3u;
  TFR(17) TFR(29) TFR(16) TFR(24)
  x0 += ks1; x1 += ks2 + 4u;
  TFR(13) TFR(15) TFR(26) TFR(6)
  x0 += ks2; x1 += ks0 + 5u;
#undef TFR
  o0 = x0; o1 = x1;
}

// Host: replicate jax.random.permutation(key(42), 4096)[:1024]  (validated absmax=0)
static void compute_sample_idx(SIdx& out) {
  static_assert(sizeof(SIdx) == 2048, "kernarg size");
  uint64_t arr[NV];
  uint16_t x[NV], tmp[NV];
  for (int i = 0; i < NV; ++i) x[i] = (uint16_t)i;
  uint32_t kh = 0u, kl = 42u;
  for (int round = 0; round < 2; ++round) {
    uint32_t nkh, nkl, sh, sl, t0, t1;
    tf2x32_host(kh, kl, 0u, 0u, nkh, nkl);
    tf2x32_host(kh, kl, 0u, 1u, sh, sl);
    kh = nkh; kl = nkl;
    for (int i = 0; i < NV; ++i) {
      tf2x32_host(sh, sl, 0u, (uint32_t)i, t0, t1);
      arr[i] = ((uint64_t)(t0 ^ t1) << 32) | (uint32_t)i;
    }
    std::sort(arr, arr + NV);
    for (int i = 0; i < NV; ++i) tmp[i] = x[(uint32_t)(arr[i] & 0xffffffffu)];
    memcpy(x, tmp, sizeof(x));
  }
  for (int i = 0; i < NPOOL; ++i) out.v[i] = x[i];
}

// ---------------- K1: 256 threads / query. float4 vertex loads, register
// distances, minima-histogram threshold + candidate rank selection,
// fused gather/max. Thread owns candidates m = tid*16 + t.
__global__ __launch_bounds__(256) void knn_pool_kernel(
    const float* __restrict__ vertices, const float* __restrict__ fm,
    const SIdx sidx,
    float* __restrict__ outV, float* __restrict__ outF) {
  __shared__ uint32_t hist[1024];
  __shared__ unsigned long long cand[64];
  __shared__ unsigned long long wmin[4];
  __shared__ int winners[KNB];
  __shared__ int s_ncand, s_taub;

  const int tid = threadIdx.x;
  const int lane = tid & 63;
  const int warp = tid >> 6;
  const int q = blockIdx.x;        // 0..8191
  const int b = q & 7;             // XCD-aware: batch b -> XCD b (bijective)
  const int i = q >> 3;
  const int n = (int)sidx.v[i];

  const float* vb = vertices + (size_t)b * NV * 3;
  const float qx = vb[n * 3 + 0], qy = vb[n * 3 + 1], qz = vb[n * 3 + 2];
  // quadratic[n]: plain mul/add (XLA reduce of squares) — validated arithmetic
  const float qn = __fadd_rn(__fadd_rn(__fmul_rn(qx, qx), __fmul_rn(qy, qy)),
                             __fmul_rn(qz, qz));

  // 12 independent float4 loads: this thread's 16 vertices, 192 B contiguous
  const float4* vb4 = (const float4*)vb + tid * 12;
  float f[48];
#pragma unroll
  for (int j = 0; j < 12; ++j) {
    const float4 v4 = vb4[j];
    f[4 * j + 0] = v4.x; f[4 * j + 1] = v4.y;
    f[4 * j + 2] = v4.z; f[4 * j + 3] = v4.w;
  }

  uint32_t d[16];
#pragma unroll
  for (int t = 0; t < 16; ++t) {
    const int m = (tid << 4) + t;
    const float cx = f[3 * t + 0], cy = f[3 * t + 1], cz = f[3 * t + 2];
    const float inner = __fmaf_rn(cz, qz, __fmaf_rn(cy, qy, __fmul_rn(cx, qx)));
    const float qm = __fadd_rn(__fadd_rn(__fmul_rn(cx, cx), __fmul_rn(cy, cy)),
                               __fmul_rn(cz, cz));
    const float dist = __fadd_rn(__fadd_rn(__fmul_rn(-2.0f, inner), qm), qn);
    d[t] = (m == n) ? REMOVED : __float_as_uint(dist);  // validated uint order
  }

  // per-thread minimum (value only)
  uint32_t mn = d[0];
#pragma unroll
  for (int t = 1; t < 16; ++t) mn = (d[t] < mn) ? d[t] : mn;

  hist[tid] = 0; hist[tid + 256] = 0; hist[tid + 512] = 0; hist[tid + 768] = 0;
  if (tid == 0) s_ncand = 0;
  __syncthreads();

  // minima histogram: 256 atomics total (vs 4096) — hot-bin serialization cut
  atomicAdd(&hist[HIDX(mn >> 22)], 1u);
  __syncthreads();

  // warp0: crossing bin taub where cumulative minima-count reaches KNB.
  // Validity: d16_overall <= 16th-smallest of per-thread minima, whose bin <= taub.
  if (warp == 0) {
    uint32_t s = 0;
#pragma unroll
    for (int j = 0; j < 16; ++j) s += hist[j * 64 + lane];  // HIDX(lane*16+j): 2-way banks
    uint32_t inc = s;
    for (int off = 1; off < 64; off <<= 1) {
      const uint32_t o = (uint32_t)__shfl_up((int)inc, off);
      if (lane >= off) inc += o;
    }
    const uint32_t pre = inc - s;
    const bool cross = (pre < KNB) && (inc >= KNB);
    const unsigned long long bal = __ballot(cross);
    const int leader = __ffsll((unsigned long long)bal) - 1;
    if (lane == leader) {
      uint32_t c = pre;
      int tb = lane * 16 + 15;
      for (int j = 0; j < 16; ++j) {
        const uint32_t h = hist[j * 64 + lane];
        if (c + h >= KNB) { tb = lane * 16 + j; break; }
        c += h;
      }
      s_taub = tb;
    }
  }
  __syncthreads();

  const uint32_t taub = (uint32_t)s_taub;

  // append all candidates with bin <= taub (superset of exact top-16; C >= 16)
#pragma unroll
  for (int t = 0; t < 16; ++t) {
    const uint32_t v = d[t];
    if ((v >> 22) <= taub) {
      const int s = atomicAdd(&s_ncand, 1);
      if (s < 64)
        cand[s] = ((unsigned long long)v << 32) | (uint32_t)((tid << 4) + t);
    }
  }
  __syncthreads();

  const int C = s_ncand;
  if (C <= 64) {
    // per-lane rank selection: exact top-16 by packed (dist, idx) u64 order
    if (warp == 0) {
      const unsigned long long me =
          (lane < C) ? cand[lane] : 0xFFFFFFFFFFFFFFFFull;
      int rank = 0;
      for (int j = 0; j < C; ++j)          // cand[j]: LDS broadcast read
        rank += (cand[j] < me) ? 1 : 0;
      if (lane < C && rank < KNB) winners[rank] = (int)(me & 0xFFFFFFFFu);
    }
    __syncthreads();
  } else {
    // rare fallback: validated 16-round extraction over predicate bin <= taub
    uint32_t mask = 0;
    for (int r = 0; r < KNB; ++r) {
      uint32_t bv = REMOVED, bm = 0xFFFFFFFFu;
#pragma unroll
      for (int t = 0; t < 16; ++t) {
        const uint32_t v = (((mask >> t) & 1u) || ((d[t] >> 22) > taub))
                               ? REMOVED : d[t];
        const uint32_t m = (uint32_t)((tid << 4) + t);
        if (v < bv || (v == bv && m < bm)) { bv = v; bm = m; }
      }
      for (int off = 32; off > 0; off >>= 1) {
        const uint32_t ov = (uint32_t)__shfl_down((int)bv, off);
        const uint32_t om = (uint32_t)__shfl_down((int)bm, off);
        if (ov < bv || (ov == bv && om < bm)) { bv = ov; bm = om; }
      }
      if (lane == 0) wmin[warp] = ((unsigned long long)bv << 32) | bm;
      __syncthreads();
      const unsigned long long p0 = wmin[0], p1 = wmin[1];
      const unsigned long long p2 = wmin[2], p3 = wmin[3];
      const unsigned long long pa = (p0 < p1) ? p0 : p1;
      const unsigned long long pb = (p2 < p3) ? p2 : p3;
      const int w = (int)(((pa < pb) ? pa : pb) & 0xFFFFFFFFu);
      if (tid == 0) winners[r] = w;
      if (tid == (w >> 4)) mask |= 1u << (w & 15);
      __syncthreads();
    }
  }

  // fused gather + max over the winner set (order-invariant)
  const float* fmb = fm + (size_t)b * NV * 256;
  float af = -INFINITY;
#pragma unroll
  for (int s = 0; s < KNB; ++s) {
    const int w = winners[s];
    af = fmaxf(af, fmb[(size_t)w * 256 + tid]);
  }
  outF[((size_t)b * NPOOL + i) * 256 + tid] = af;

  if (tid < 3) {
    outV[((size_t)b * NPOOL + i) * 3 + tid] = vb[n * 3 + tid];
  }
}

extern "C" void kernel_launch(void* const* d_in, const int* in_sizes, int n_in,
                              void* d_out, int out_size, void* d_ws, size_t ws_size,
                              hipStream_t stream) {
  const float* vertices = (const float*)d_in[0];
  const float* fm = (const float*)d_in[1];
  float* out = (float*)d_out;
  float* outV = out;                      // (8, 1024, 3)
  float* outF = out + NB * NPOOL * 3;     // (8, 1024, 256)

  SIdx sidx;
  compute_sample_idx(sidx);               // pure host constant of key(42)

  knn_pool_kernel<<<NB * NPOOL, 256, 0, stream>>>(vertices, fm, sidx, outV, outF);
}

// Round 11
// 36.098 us; speedup vs baseline: 3.8165x; 1.1348x over previous
//
#include <hip/hip_runtime.h>
#include <stdint.h>
#include <string.h>
#include <algorithm>

#define NV 4096
#define NPOOL 1024
#define NB 8
#define KNB 16
#define REMOVED 0xFFFFFFFFu
// bank-deconflicted histogram index: bin b -> word (b>>4) | ((b&15)<<6)
#define HIDX(b) ((((b) >> 4) | (((b) & 15) << 6)))

struct SIdx { unsigned short v[NPOOL]; };  // 2 KB by-value kernel arg

// ---------------- Threefry-2x32 (JAX-compatible, 20 rounds), host ----------
static inline void tf2x32_host(uint32_t k0, uint32_t k1,
                               uint32_t c0, uint32_t c1,
                               uint32_t& o0, uint32_t& o1) {
  uint32_t ks0 = k0, ks1 = k1, ks2 = k0 ^ k1 ^ 0x1BD11BDAu;
  uint32_t x0 = c0 + ks0, x1 = c1 + ks1;
#define TFR(r) { x0 += x1; x1 = (x1 << (r)) | (x1 >> (32 - (r))); x1 ^= x0; }
  TFR(13) TFR(15) TFR(26) TFR(6)
  x0 += ks1; x1 += ks2 + 1u;
  TFR(17) TFR(29) TFR(16) TFR(24)
  x0 += ks2; x1 += ks0 + 2u;
  TFR(13) TFR(15) TFR(26) TFR(6)
  x0 += ks0; x1 += ks1 + 3u;
  TFR(17) TFR(29) TFR(16) TFR(24)
  x0 += ks1; x1 += ks2 + 4u;
  TFR(13) TFR(15) TFR(26) TFR(6)
  x0 += ks2; x1 += ks0 + 5u;
#undef TFR
  o0 = x0; o1 = x1;
}

// Host: replicate jax.random.permutation(key(42), 4096)[:1024]  (validated absmax=0)
static void compute_sample_idx(SIdx& out) {
  static_assert(sizeof(SIdx) == 2048, "kernarg size");
  uint64_t arr[NV];
  uint16_t x[NV], tmp[NV];
  for (int i = 0; i < NV; ++i) x[i] = (uint16_t)i;
  uint32_t kh = 0u, kl = 42u;
  for (int round = 0; round < 2; ++round) {
    uint32_t nkh, nkl, sh, sl, t0, t1;
    tf2x32_host(kh, kl, 0u, 0u, nkh, nkl);
    tf2x32_host(kh, kl, 0u, 1u, sh, sl);
    kh = nkh; kl = nkl;
    for (int i = 0; i < NV; ++i) {
      tf2x32_host(sh, sl, 0u, (uint32_t)i, t0, t1);
      arr[i] = ((uint64_t)(t0 ^ t1) << 32) | (uint32_t)i;
    }
    std::sort(arr, arr + NV);
    for (int i = 0; i < NV; ++i) tmp[i] = x[(uint32_t)(arr[i] & 0xffffffffu)];
    memcpy(x, tmp, sizeof(x));
  }
  for (int i = 0; i < NPOOL; ++i) out.v[i] = x[i];
}

// validated 16-round extraction fallback (rare), predicate bin <= TAUB
#define FALLBACK(D, TAUB, WIN)                                             \
  {                                                                        \
    uint32_t mask = 0;                                                     \
    for (int r = 0; r < KNB; ++r) {                                        \
      uint32_t bv = REMOVED, bm = 0xFFFFFFFFu;                             \
      _Pragma("unroll")                                                    \
      for (int t = 0; t < 16; ++t) {                                       \
        const uint32_t v = (((mask >> t) & 1u) || ((D[t] >> 22) > (TAUB))) \
                               ? REMOVED : D[t];                           \
        const uint32_t m = (uint32_t)((tid << 4) + t);                     \
        if (v < bv || (v == bv && m < bm)) { bv = v; bm = m; }             \
      }                                                                    \
      for (int off = 32; off > 0; off >>= 1) {                             \
        const uint32_t ov = (uint32_t)__shfl_down((int)bv, off);           \
        const uint32_t om = (uint32_t)__shfl_down((int)bm, off);           \
        if (ov < bv || (ov == bv && om < bm)) { bv = ov; bm = om; }        \
      }                                                                    \
      if (lane == 0) wmin[warp] = ((unsigned long long)bv << 32) | bm;     \
      __syncthreads();                                                     \
      const unsigned long long p0 = wmin[0], p1 = wmin[1];                 \
      const unsigned long long p2 = wmin[2], p3 = wmin[3];                 \
      const unsigned long long pa = (p0 < p1) ? p0 : p1;                   \
      const unsigned long long pb = (p2 < p3) ? p2 : p3;                   \
      const int w = (int)(((pa < pb) ? pa : pb) & 0xFFFFFFFFu);            \
      if (tid == 0) (WIN)[r] = w;                                          \
      if (tid == (w >> 4)) mask |= 1u << (w & 15);                         \
      __syncthreads();                                                     \
    }                                                                      \
  }

// ---------------- K1: 256 threads / 2 queries (same batch). Shared vertex
// registers, dual minima-histogram selection on parallel warps, float4 gather.
__global__ __launch_bounds__(256) void knn_pool_kernel(
    const float* __restrict__ vertices, const float* __restrict__ fm,
    const SIdx sidx,
    float* __restrict__ outV, float* __restrict__ outF) {
  __shared__ uint32_t hist0[1024], hist1[1024];
  __shared__ unsigned long long cand0[64], cand1[64];
  __shared__ unsigned long long wmin[4];
  __shared__ int winners0[KNB], winners1[KNB];
  __shared__ int s_nc0, s_nc1, s_tb0, s_tb1;

  const int tid = threadIdx.x;
  const int lane = tid & 63;
  const int warp = tid >> 6;
  const int blk = blockIdx.x;      // 0..4095
  const int b = blk & 7;           // XCD-aware: batch b -> XCD b (bijective)
  const int i0 = (blk >> 3) << 1;
  const int i1 = i0 | 1;
  const int n0 = (int)sidx.v[i0];
  const int n1 = (int)sidx.v[i1];

  const float* vb = vertices + (size_t)b * NV * 3;
  const float q0x = vb[n0 * 3 + 0], q0y = vb[n0 * 3 + 1], q0z = vb[n0 * 3 + 2];
  const float q1x = vb[n1 * 3 + 0], q1y = vb[n1 * 3 + 1], q1z = vb[n1 * 3 + 2];
  // quadratic[n]: plain mul/add (XLA reduce of squares) — validated arithmetic
  const float qn0 = __fadd_rn(__fadd_rn(__fmul_rn(q0x, q0x), __fmul_rn(q0y, q0y)),
                              __fmul_rn(q0z, q0z));
  const float qn1 = __fadd_rn(__fadd_rn(__fmul_rn(q1x, q1x), __fmul_rn(q1y, q1y)),
                              __fmul_rn(q1z, q1z));

  // 12 independent float4 loads: this thread's 16 vertices, 192 B contiguous
  const float4* vb4 = (const float4*)vb + tid * 12;
  float f[48];
#pragma unroll
  for (int j = 0; j < 12; ++j) {
    const float4 v4 = vb4[j];
    f[4 * j + 0] = v4.x; f[4 * j + 1] = v4.y;
    f[4 * j + 2] = v4.z; f[4 * j + 3] = v4.w;
  }

  uint32_t d0[16], d1[16];
#pragma unroll
  for (int t = 0; t < 16; ++t) {
    const int m = (tid << 4) + t;
    const float cx = f[3 * t + 0], cy = f[3 * t + 1], cz = f[3 * t + 2];
    const float qm = __fadd_rn(__fadd_rn(__fmul_rn(cx, cx), __fmul_rn(cy, cy)),
                               __fmul_rn(cz, cz));  // shared between queries
    const float in0 = __fmaf_rn(cz, q0z, __fmaf_rn(cy, q0y, __fmul_rn(cx, q0x)));
    const float in1 = __fmaf_rn(cz, q1z, __fmaf_rn(cy, q1y, __fmul_rn(cx, q1x)));
    const float ds0 = __fadd_rn(__fadd_rn(__fmul_rn(-2.0f, in0), qm), qn0);
    const float ds1 = __fadd_rn(__fadd_rn(__fmul_rn(-2.0f, in1), qm), qn1);
    d0[t] = (m == n0) ? REMOVED : __float_as_uint(ds0);  // validated uint order
    d1[t] = (m == n1) ? REMOVED : __float_as_uint(ds1);
  }

  // per-thread minima
  uint32_t mn0 = d0[0], mn1 = d1[0];
#pragma unroll
  for (int t = 1; t < 16; ++t) {
    mn0 = (d0[t] < mn0) ? d0[t] : mn0;
    mn1 = (d1[t] < mn1) ? d1[t] : mn1;
  }

  const uint4 z4 = make_uint4(0, 0, 0, 0);
  ((uint4*)hist0)[tid] = z4;   // 256 * 16B = 4 KB each
  ((uint4*)hist1)[tid] = z4;
  if (tid == 0) { s_nc0 = 0; s_nc1 = 0; }
  __syncthreads();

  // minima histograms: 2 atomics/thread
  atomicAdd(&hist0[HIDX(mn0 >> 22)], 1u);
  atomicAdd(&hist1[HIDX(mn1 >> 22)], 1u);
  __syncthreads();

  // parallel scans: warp0 -> hist0 -> s_tb0 ; warp1 -> hist1 -> s_tb1
  if (warp < 2) {
    uint32_t* H = (warp == 0) ? hist0 : hist1;   // wave-uniform
    uint32_t s = 0;
#pragma unroll
    for (int j = 0; j < 16; ++j) s += H[j * 64 + lane];  // HIDX(lane*16+j)
    uint32_t inc = s;
    for (int off = 1; off < 64; off <<= 1) {
      const uint32_t o = (uint32_t)__shfl_up((int)inc, off);
      if (lane >= off) inc += o;
    }
    const uint32_t pre = inc - s;
    const bool cross = (pre < KNB) && (inc >= KNB);
    const unsigned long long bal = __ballot(cross);
    const int leader = __ffsll((unsigned long long)bal) - 1;
    if (lane == leader) {
      uint32_t c = pre;
      int tb = lane * 16 + 15;
      for (int j = 0; j < 16; ++j) {
        const uint32_t h = H[j * 64 + lane];
        if (c + h >= KNB) { tb = lane * 16 + j; break; }
        c += h;
      }
      if (warp == 0) s_tb0 = tb; else s_tb1 = tb;
    }
  }
  __syncthreads();

  const uint32_t taub0 = (uint32_t)s_tb0;
  const uint32_t taub1 = (uint32_t)s_tb1;

  // append candidates with bin <= taub (superset of exact top-16; C >= 16)
#pragma unroll
  for (int t = 0; t < 16; ++t) {
    const uint32_t v0 = d0[t];
    if ((v0 >> 22) <= taub0) {
      const int s = atomicAdd(&s_nc0, 1);
      if (s < 64)
        cand0[s] = ((unsigned long long)v0 << 32) | (uint32_t)((tid << 4) + t);
    }
    const uint32_t v1 = d1[t];
    if ((v1 >> 22) <= taub1) {
      const int s = atomicAdd(&s_nc1, 1);
      if (s < 64)
        cand1[s] = ((unsigned long long)v1 << 32) | (uint32_t)((tid << 4) + t);
    }
  }
  __syncthreads();

  const int C0 = s_nc0, C1 = s_nc1;
  // per-lane rank selection on parallel warps (exact top-16 by (dist,idx) u64)
  if (warp == 0 && C0 <= 64) {
    const unsigned long long me =
        (lane < C0) ? cand0[lane] : 0xFFFFFFFFFFFFFFFFull;
    int rank = 0;
    for (int j = 0; j < C0; ++j) rank += (cand0[j] < me) ? 1 : 0;
    if (lane < C0 && rank < KNB) winners0[rank] = (int)(me & 0xFFFFFFFFu);
  }
  if (warp == 1 && C1 <= 64) {
    const unsigned long long me =
        (lane < C1) ? cand1[lane] : 0xFFFFFFFFFFFFFFFFull;
    int rank = 0;
    for (int j = 0; j < C1; ++j) rank += (cand1[j] < me) ? 1 : 0;
    if (lane < C1 && rank < KNB) winners1[rank] = (int)(me & 0xFFFFFFFFu);
  }
  __syncthreads();

  // rare fallbacks (block-uniform conditions, barriers inside)
  if (C0 > 64) FALLBACK(d0, taub0, winners0);
  if (C1 > 64) FALLBACK(d1, taub1, winners1);

  // gather + max: warp w handles query w with float4 rows (order-invariant)
  const float* fmb = fm + (size_t)b * NV * 256;
  if (warp < 2) {
    const int* W = (warp == 0) ? winners0 : winners1;
    const int ii = (warp == 0) ? i0 : i1;
    float4 acc = make_float4(-INFINITY, -INFINITY, -INFINITY, -INFINITY);
#pragma unroll
    for (int s = 0; s < KNB; ++s) {
      const float4 v = ((const float4*)(fmb + (size_t)W[s] * 256))[lane];
      acc.x = fmaxf(acc.x, v.x); acc.y = fmaxf(acc.y, v.y);
      acc.z = fmaxf(acc.z, v.z); acc.w = fmaxf(acc.w, v.w);
    }
    ((float4*)(outF + ((size_t)b * NPOOL + ii) * 256))[lane] = acc;
  }
  if (warp == 2 && lane < 3) outV[((size_t)b * NPOOL + i0) * 3 + lane] = vb[n0 * 3 + lane];
  if (warp == 3 && lane < 3) outV[((size_t)b * NPOOL + i1) * 3 + lane] = vb[n1 * 3 + lane];
}

extern "C" void kernel_launch(void* const* d_in, const int* in_sizes, int n_in,
                              void* d_out, int out_size, void* d_ws, size_t ws_size,
                              hipStream_t stream) {
  const float* vertices = (const float*)d_in[0];
  const float* fm = (const float*)d_in[1];
  float* out = (float*)d_out;
  float* outV = out;                      // (8, 1024, 3)
  float* outF = out + NB * NPOOL * 3;     // (8, 1024, 256)

  SIdx sidx;
  compute_sample_idx(sidx);               // pure host constant of key(42)

  knn_pool_kernel<<<NB * NPOOL / 2, 256, 0, stream>>>(vertices, fm, sidx, outV, outF);
}